// Round 8
// baseline (7225.575 us; speedup 1.0000x reference)
//
#include <hip/hip_runtime.h>
#include <math.h>

#define BB 256
#define TIN 32
#define TOUT 29
#define VDEC 72
#define EDIM 256
#define HDIM 256
#define DD 6
#define BH (BB*HDIM)
#define NBLK 256

typedef unsigned short u16;
typedef unsigned int u32;
typedef __bf16 bf16x8 __attribute__((ext_vector_type(8)));
typedef float f32x4 __attribute__((ext_vector_type(4)));
typedef u16 u16x8 __attribute__((ext_vector_type(8)));

__device__ __forceinline__ float sigmf(float x){ return 1.0f/(1.0f+__expf(-x)); }
__device__ __forceinline__ float tanhf_fast(float x){ return 1.0f - 2.0f/(1.0f+__expf(2.0f*x)); }
__device__ __forceinline__ u16 f2bf(float f){
  u32 u = __builtin_bit_cast(u32, f);
  u32 r = (u + 0x7fffu + ((u>>16)&1u)) >> 16;   // RNE; inputs finite
  return (u16)r;
}
__device__ __forceinline__ float bf2f(u16 s){
  u32 u = ((u32)s)<<16; return __builtin_bit_cast(float, u);
}
__device__ __forceinline__ bf16x8 ldbf8(const u16* p){
  u16x8 t = *(const u16x8*)p; return __builtin_bit_cast(bf16x8, t);
}
// volatile = sc0 = L1-bypass: cross-block data reads
__device__ __forceinline__ bf16x8 ldbf8v(const u16* p){
  u16x8 t = *(const volatile u16x8*)p; return __builtin_bit_cast(bf16x8, t);
}
__device__ __forceinline__ float ldbfv(const u16* p){ return bf2f(*(const volatile u16*)p); }
__device__ __forceinline__ float ldfv(const float* p){ return *(const volatile float*)p; }
__device__ __forceinline__ f32x4 mfma16(bf16x8 a, bf16x8 b, f32x4 c){
  return __builtin_amdgcn_mfma_f32_16x16x32_bf16(a, b, c, 0, 0, 0);
}

// ---------------- shared memory union (~76 KB) ----------------
struct GmS { float As[32][33]; float Ws[256][34]; };
union SharedU {
  struct { float Gt[2][4][32][18]; } st;          // decoder stage partial sums
  struct { u16 hprev[16][264]; } enc;             // encoder recurrent h (pad 264: 2-way banks)
  GmS gm2[2];
  struct { float s[512]; float p4[VDEC][4]; float lg[VDEC]; float ctxp[2][256]; int tok; } fc;
};

// ---------------- barriers ----------------
// barblk u32: [0..255] slow arr; [320] slow gen; [336..343] xcd ctrs; [352] badflag;
// [384+mt*32] fast cnt (monotonic); [384+mt*32+16] fast gen.
// slow: full agent release/acquire grid barrier (round-2 proven; release emits L2
//       writeback, acquire invalidates) — used where cross-XCD plain-store data hands off.
// fast: agent-scope relaxed, per-XCD counter (round-5/6 proven). Data visibility from
//       vmcnt-drain at __syncthreads + same-XCD-L2 volatile reads.
__device__ __forceinline__ void bar_slow(u32* barblk, u32 gs, int bid){
  __syncthreads();
  u32* arr = barblk;
  u32* gen = barblk + 320;
  if (threadIdx.x == 0)
    __hip_atomic_store(&arr[bid], gs, __ATOMIC_RELEASE, __HIP_MEMORY_SCOPE_AGENT);
  if (bid == 0){
    if (threadIdx.x < 256)
      while (__hip_atomic_load(&arr[threadIdx.x], __ATOMIC_RELAXED, __HIP_MEMORY_SCOPE_AGENT) < gs)
        __builtin_amdgcn_s_sleep(8);
    __syncthreads();
    if (threadIdx.x == 0)
      __hip_atomic_store(gen, gs, __ATOMIC_RELEASE, __HIP_MEMORY_SCOPE_AGENT);
  } else if (threadIdx.x == 0){
    while (__hip_atomic_load(gen, __ATOMIC_RELAXED, __HIP_MEMORY_SCOPE_AGENT) < gs)
      __builtin_amdgcn_s_sleep(8);
  }
  __builtin_amdgcn_fence(__ATOMIC_ACQUIRE, "agent");
  __syncthreads();
}

__device__ __forceinline__ void bar_fast(u32* barblk, int mt, u32 gf){
  __syncthreads();
  u32* cnt  = barblk + 384 + mt*32;
  u32* genx = cnt + 16;
  if (threadIdx.x == 0){
    u32 old = __hip_atomic_fetch_add(cnt, 1u, __ATOMIC_RELAXED, __HIP_MEMORY_SCOPE_AGENT);
    if (old == gf*32u - 1u)
      __hip_atomic_store(genx, gf, __ATOMIC_RELAXED, __HIP_MEMORY_SCOPE_AGENT);
    else
      while (__hip_atomic_load(genx, __ATOMIC_RELAXED, __HIP_MEMORY_SCOPE_AGENT) < gf)
        __builtin_amdgcn_s_sleep(1);
  }
  __syncthreads();
}

// ---------------- setup kernels ----------------
__global__ void fill_zero_u32(u32* __restrict__ p, int n){
  int i = blockIdx.x*256 + threadIdx.x;
  if (i < n) p[i] = 0u;
}

__global__ void init_out_kernel(float* __restrict__ out, int n){
  int i = blockIdx.x*256 + threadIdx.x;
  if (i >= n) return;
  float v = 0.0f;
  if (i < BB*VDEC && (i % VDEC) == 1) v = 1.0f;   // pred0 one-hot
  out[i] = v;
}

__global__ void bias2d_kernel(const float* __restrict__ W2a, const float* __restrict__ b1a, const float* __restrict__ b2a,
                              const float* __restrict__ W2h, const float* __restrict__ b1h, const float* __restrict__ b2h,
                              const float* __restrict__ W2c, const float* __restrict__ b1c, const float* __restrict__ b2c,
                              float* __restrict__ outp){
  int g = threadIdx.x;
  const float* W2[3] = {W2a, W2h, W2c};
  const float* b1[3] = {b1a, b1h, b1c};
  const float* b2[3] = {b2a, b2h, b2c};
  for (int p = 0; p < 3; p++)
    for (int m = 0; m < 6; m++){
      float s = 0.f;
      for (int l = 0; l < 6; l++) s += W2[p][m*6+l];
      outp[p*1536 + m*256 + g] = s * b1[p][g] + b2[p][m];
    }
}

__global__ void embed_enc_kernel(const int* __restrict__ input, const float* __restrict__ enc_emb,
                                 u16* __restrict__ x_emb){
  int i = blockIdx.x*256 + threadIdx.x;
  int e = i & 255, b = (i >> 8) & 255, t = i >> 16;
  x_emb[i] = f2bf(enc_emb[(size_t)input[b*TIN + t]*EDIM + e]);
}

__global__ void pack_w_kernel(const float* __restrict__ Wih, const float* __restrict__ Whh,
                              u16* __restrict__ dst, int K1, int K){
  int k = blockIdx.x*256 + threadIdx.x;
  int row = blockIdx.y;
  int d = row >> 10, rr = row & 1023;
  int ht = rr >> 6, r = rr & 63;
  int g = (r>>4)*256 + ht*16 + (r&15);
  float v;
  if (k < K1) v = Wih[((size_t)d*1024 + g)*K1 + k];
  else        v = Whh[((size_t)d*1024 + g)*256 + (k - K1)];
  dst[(size_t)row*K + k] = f2bf(v);
}

__global__ void pack_wfused_kernel(const float* __restrict__ Wih0, const float* __restrict__ attn_W,
                                   const float* __restrict__ Whh, u16* __restrict__ dst){
  int k = blockIdx.x*256 + threadIdx.x;
  int row = blockIdx.y;
  int d = row >> 10, rr = row & 1023;
  int ht = rr >> 6, r = rr & 63;
  int g = (r>>4)*256 + ht*16 + (r&15);
  float v;
  if (k >= 512) v = Whh[((size_t)d*1024 + g)*256 + (k - 512)];
  else {
    const float* wr = Wih0 + ((size_t)d*1024 + g)*256;
    float s = 0.f;
    #pragma unroll 4
    for (int o = 0; o < 256; o++) s += wr[o] * attn_W[(size_t)o*512 + k];
    v = s;
  }
  dst[(size_t)row*768 + k] = f2bf(v);
}

__global__ void biasfold_kernel(const float* __restrict__ Wih0, const float* __restrict__ attn_b,
                                const float* __restrict__ dec_b, float* __restrict__ outb){
  int i = blockIdx.x*256 + threadIdx.x;
  int d = i >> 10, g = i & 1023;
  const float* wr = Wih0 + ((size_t)d*1024 + g)*256;
  float s = dec_b[d*1024 + g];
  #pragma unroll 4
  for (int o = 0; o < 256; o++) s += wr[o]*attn_b[o];
  outb[i] = s;
}

// ---------------- encoder layer pass: one block = (16 batch rows, one dir), all 32 t ----------------
// Recurrence block-local: h in LDS, c in registers. No inter-block sync inside the pass.
// Wave wv owns ht pair {2wv, 2wv+1} x all 4 gates -> epilogue fully in-wave.
// K1 = global input cols (256: x_emb; 512: two hseq planes); + 256 recurrent cols from LDS.
template<int K1>
__device__ __forceinline__ void enc_pass(SharedU* shp, int m0, int d,
    const u16* __restrict__ g0, const u16* __restrict__ g1, size_t gtstride,
    const u16* __restrict__ Wpk, const float* __restrict__ bias_d,
    u16* __restrict__ hseq_p, float* __restrict__ hall_p, float* __restrict__ encc_p){
  constexpr int K = K1 + 256;
  const int tid = threadIdx.x;
  const int wv = tid >> 6, lane = tid & 63;
  const int r = lane & 15, lq = lane >> 4;
  // zero recurrent h
  for (int i = tid; i < 16*264; i += 512) ((u16*)shp->enc.hprev)[i] = 0;
  __syncthreads();
  // weight row pointers: tile i = ht2*4+q -> packed row (d*16 + wv*2+ht2)*64 + q*16 + r
  const u16* wrow[8];
  #pragma unroll
  for (int ht2 = 0; ht2 < 2; ht2++)
    #pragma unroll
    for (int q = 0; q < 4; q++)
      wrow[ht2*4+q] = Wpk + (size_t)((d*16 + wv*2 + ht2)*64 + q*16 + r)*K + lq*8;
  float c8[8];
  #pragma unroll
  for (int i = 0; i < 8; i++) c8[i] = 0.f;
  const int mb = lq*4;
  #pragma unroll 1
  for (int t = 0; t < TIN; t++){
    f32x4 acc[8];
    #pragma unroll
    for (int i = 0; i < 8; i++) acc[i] = (f32x4){0.f,0.f,0.f,0.f};
    #pragma unroll
    for (int k0 = 0; k0 < K; k0 += 32){
      bf16x8 a;
      if (k0 < K1){
        const u16* gp = (K1 == 512 && k0 >= 256) ? g1 : g0;
        a = ldbf8v(gp + (size_t)t*gtstride + (size_t)(m0 + r)*256 + (k0 & 255) + lq*8);
      } else {
        a = ldbf8(&shp->enc.hprev[r][(k0 - K1) + lq*8]);
      }
      #pragma unroll
      for (int i = 0; i < 8; i++)
        acc[i] = mfma16(a, ldbf8(wrow[i] + k0), acc[i]);
    }
    __syncthreads();                       // hprev reads done before overwrite
    #pragma unroll
    for (int ht2 = 0; ht2 < 2; ht2++){
      int h = (wv*2 + ht2)*16 + r;
      #pragma unroll
      for (int reg = 0; reg < 4; reg++){
        float iv = acc[ht2*4+0][reg] + bias_d[h];
        float fv = acc[ht2*4+1][reg] + bias_d[256 + h];
        float gv = acc[ht2*4+2][reg] + bias_d[512 + h];
        float ov = acc[ht2*4+3][reg] + bias_d[768 + h];
        float co = c8[ht2*4+reg];
        float cc = sigmf(fv)*co + sigmf(iv)*tanhf_fast(gv);
        float hv = sigmf(ov)*tanhf_fast(cc);
        c8[ht2*4+reg] = cc;
        u16 hb = f2bf(hv);
        shp->enc.hprev[mb + reg][h] = hb;
        size_t go = (size_t)(m0 + mb + reg)*256 + h;
        hseq_p[(size_t)t*(DD*BH) + go] = hb;        // plain store; slow barrier publishes
        hall_p[(size_t)t*(DD*BH) + go] = hv;
      }
    }
    __syncthreads();                       // hprev(t) complete before next t reads
  }
  // final cell state -> enc_c plane
  #pragma unroll
  for (int ht2 = 0; ht2 < 2; ht2++){
    int h = (wv*2 + ht2)*16 + r;
    #pragma unroll
    for (int reg = 0; reg < 4; reg++)
      encc_p[(size_t)(m0 + mb + reg)*256 + h] = c8[ht2*4+reg];
  }
}

// ---------------- decoder stage (round-6 proven structure) ----------------
template<int K1>
__device__ __forceinline__ void stage_dec(SharedU* shp, int mt, int y,
    const u16* __restrict__ inp, const u16* __restrict__ Wpk, const float* __restrict__ bias_l,
    const u16* __restrict__ hR, u16* __restrict__ hW, float* __restrict__ cBuf,
    u16* __restrict__ inp_out, int l){
  auto& ss = shp->st;
  constexpr int K = K1 + 256;
  constexpr int HK = K/2;
  int tid = threadIdx.x;
  int m_base = mt*32;
  int d = y >> 4, ht = y & 15;
  int idx = 2*l + d;
  int q8 = tid >> 6, lane = tid & 63;
  int qg = q8 & 3, kh2 = q8 >> 2;
  int r = lane & 15, lq = lane >> 4;
  const u16* a0p = inp + (size_t)(m_base + r)*K1 + lq*8;
  const u16* a1p = a0p + (size_t)16*K1;
  const u16* h0p = hR + (size_t)idx*BH + (size_t)(m_base + r)*HDIM + lq*8;
  const u16* h1p = h0p + 16*HDIM;
  const u16* wp  = Wpk + (size_t)((d*16+ht)*64 + qg*16 + r)*K + lq*8;
  const int cbase = kh2*HK;
  f32x4 acc0 = {0.f,0.f,0.f,0.f}, acc1 = {0.f,0.f,0.f,0.f};
  #pragma unroll
  for (int c = 0; c < HK; c += 32){
    int col = cbase + c;
    bool ina = (col < K1);
    const u16* pa0 = ina ? (a0p + col) : (h0p + (col - K1));
    const u16* pa1 = ina ? (a1p + col) : (h1p + (col - K1));
    bf16x8 a0 = ldbf8v(pa0);
    bf16x8 a1 = ldbf8v(pa1);
    bf16x8 bq = ldbf8(wp + col);
    acc0 = mfma16(a0, bq, acc0);
    acc1 = mfma16(a1, bq, acc1);
  }
  __syncthreads();
  #pragma unroll
  for (int rr = 0; rr < 4; rr++){
    ss.Gt[kh2][qg][lq*4 + rr][r]      = acc0[rr];
    ss.Gt[kh2][qg][16 + lq*4 + rr][r] = acc1[rr];
  }
  __syncthreads();
  {
    const float* bias = bias_l + d*1024;
    int bb = tid >> 4, h2 = tid & 15;
    int b = m_base + bb, h = ht*16 + h2;
    float iv = ss.Gt[0][0][bb][h2] + ss.Gt[1][0][bb][h2] + bias[h];
    float fv = ss.Gt[0][1][bb][h2] + ss.Gt[1][1][bb][h2] + bias[256 + h];
    float gv = ss.Gt[0][2][bb][h2] + ss.Gt[1][2][bb][h2] + bias[512 + h];
    float ov = ss.Gt[0][3][bb][h2] + ss.Gt[1][3][bb][h2] + bias[768 + h];
    size_t off = (size_t)idx*BH + (size_t)b*HDIM + h;
    float cold = cBuf[off];
    float cc = sigmf(fv)*cold + sigmf(iv)*tanhf_fast(gv);
    float hv = sigmf(ov)*tanhf_fast(cc);
    cBuf[off] = cc;
    u16 hb = f2bf(hv);
    hW[off] = hb;
    if (inp_out) inp_out[(size_t)b*512 + d*HDIM + h] = hb;
  }
}

// ---------------- 6x6 layer-mix for one (b,h) at timestep t ----------------
__device__ __forceinline__ void mix_one(int b, int h, const float* __restrict__ inp,
    float* __restrict__ outp, const float* __restrict__ W2, int t){
  size_t base2 = ((size_t)t*6)*BH + (size_t)b*256 + h;
  float v[6];
  #pragma unroll
  for (int l = 0; l < 6; l++) v[l] = ldfv(&inp[base2 + (size_t)l*BH]);
  #pragma unroll
  for (int m = 0; m < 6; m++){
    float s = 0.f;
    #pragma unroll
    for (int l = 0; l < 6; l++) s += W2[m*6+l]*v[l];
    outp[base2 + (size_t)m*BH] = s;
  }
}

// ---------------- fp32 gemm tile (256 threads; conflict-free Ws reads) ----------------
__device__ __forceinline__ void gemm_tile(GmS& sg, int tid, int m_base,
    const float* __restrict__ A, float* __restrict__ C, const float* __restrict__ W,
    const float* __restrict__ bias2d, u16* __restrict__ Cbf){
  int rg = tid >> 5, cg = tid & 31;
  float acc[4][8];
  #pragma unroll
  for (int i=0;i<4;i++)
    #pragma unroll
    for (int j=0;j<8;j++) acc[i][j]=0.f;
  for (int k0 = 0; k0 < 256; k0 += 32){
    #pragma unroll
    for (int p=0;p<4;p++) sg.As[rg + p*8][cg] = ldfv(&A[(size_t)(m_base + rg + p*8)*256 + k0 + cg]);
    #pragma unroll
    for (int p=0;p<32;p++) sg.Ws[rg + p*8][cg] = W[(size_t)(rg + p*8)*256 + k0 + cg];
    __syncthreads();
    #pragma unroll
    for (int kk=0; kk<32; kk++){
      float a[4], w[8];
      #pragma unroll
      for (int i=0;i<4;i++) a[i] = sg.As[rg*4+i][kk];
      #pragma unroll
      for (int j=0;j<8;j++) w[j] = sg.Ws[cg + 32*j][kk];
      #pragma unroll
      for (int i=0;i<4;i++)
        #pragma unroll
        for (int j=0;j<8;j++) acc[i][j] += a[i]*w[j];
    }
    __syncthreads();
  }
  #pragma unroll
  for (int i=0;i<4;i++){
    int row = m_base + rg*4 + i;
    int bm = (row >> 8) % 6;
    #pragma unroll
    for (int j=0;j<8;j++){
      int col = cg + 32*j;
      float v = acc[i][j] + bias2d[bm*256 + col];
      if (C)   C[(size_t)row*256 + col] = v;
      if (Cbf) Cbf[(size_t)row*256 + col] = f2bf(v);
    }
  }
}

// ---------------- attention ctx + fc(prev step) + token embed (512 thr) ----------------
__device__ __forceinline__ void attn_phase(SharedU* shp, int b, int step,
    const u16* __restrict__ hR, const u16* __restrict__ eo, u16* __restrict__ cat,
    const int* __restrict__ tf, float* __restrict__ attn_out,
    const int* __restrict__ target, float* __restrict__ outp,
    const float* __restrict__ dec_emb, const u16* __restrict__ top,
    const float* __restrict__ fc_W, const float* __restrict__ fc_b){
  auto& sf = shp->fc;
  int tid = threadIdx.x;
  if (step > 0){
    sf.s[tid] = ldbfv(&top[(size_t)b*512 + tid]);
    __syncthreads();
    if (tid < 4*VDEC){
      int v = tid >> 2, part = tid & 3;
      int k0 = part*128;
      const float* wr = fc_W + (size_t)v*512;
      float a = 0.f;
      #pragma unroll 4
      for (int k = k0; k < k0+128; k++) a += sf.s[k]*wr[k];
      sf.p4[v][part] = a;
    }
    __syncthreads();
    if (tid < VDEC){
      float a = fc_b[tid] + sf.p4[tid][0] + sf.p4[tid][1] + sf.p4[tid][2] + sf.p4[tid][3];
      outp[((size_t)step*BB + b)*VDEC + tid] = a;
      sf.lg[tid] = a;
    }
    __syncthreads();
  }
  int tok;
  if (tf[0]) tok = target[b*TOUT + step];
  else if (step == 0) tok = 1;
  else {
    if (tid == 0){
      int bi = 0; float bv = sf.lg[0];
      for (int v = 1; v < VDEC; v++){ float x = sf.lg[v]; if (x > bv){ bv = x; bi = v; } }
      sf.tok = bi;
    }
    __syncthreads();
    tok = sf.tok;
  }
  if (tid < 256) cat[(size_t)b*512 + tid] = f2bf(dec_emb[(size_t)tok*EDIM + tid]);
  int hc = tid & 255, dhalf = tid >> 8;
  bool wa = (tf[0] == 0);
  float acc = 0.f;
  for (int dd = 0; dd < 3; dd++){
    int d = dhalf*3 + dd;
    float hv = ldbfv(&hR[(size_t)d*BH + (size_t)b*256 + hc]);
    const u16* ep = eo + (size_t)d*BH + (size_t)b*256 + hc;
    float se = 0.f, ac = 0.f;
    #pragma unroll 8
    for (int t = 0; t < TIN; t++){
      float ev = bf2f(ep[(size_t)t*(DD*BH)]);
      float e = __expf(hv*ev);
      se += e; ac += e*ev;
    }
    acc += ac/se;
    if (wa){
      float inv = 1.f/se;
      for (int t = 0; t < TIN; t++){
        float ev = bf2f(ep[(size_t)t*(DD*BH)]);
        atomicAdd(&attn_out[(((size_t)(step+1)*TIN + t)*DD + d)*BB + b], __expf(hv*ev)*inv);
      }
    }
  }
  sf.ctxp[dhalf][hc] = acc;
  __syncthreads();
  if (tid < 256)
    cat[(size_t)b*512 + 256 + tid] = f2bf((sf.ctxp[0][tid] + sf.ctxp[1][tid])*(1.0f/6.0f));
}

__device__ __forceinline__ void fc_final_phase(SharedU* shp, int b,
    const u16* __restrict__ top, const float* __restrict__ fc_W,
    const float* __restrict__ fc_b, float* __restrict__ outp){
  auto& sf = shp->fc;
  int tid = threadIdx.x;
  sf.s[tid] = ldbfv(&top[(size_t)b*512 + tid]);
  __syncthreads();
  if (tid < 4*VDEC){
    int v = tid >> 2, part = tid & 3;
    int k0 = part*128;
    const float* wr = fc_W + (size_t)v*512;
    float a = 0.f;
    #pragma unroll 4
    for (int k = k0; k < k0+128; k++) a += sf.s[k]*wr[k];
    sf.p4[v][part] = a;
  }
  __syncthreads();
  if (tid < VDEC){
    float a = fc_b[tid] + sf.p4[tid][0] + sf.p4[tid][1] + sf.p4[tid][2] + sf.p4[tid][3];
    outp[((size_t)(TOUT-1)*BB + b)*VDEC + tid] = a;
  }
}

// ---------------- THE megakernel ----------------
__global__ __launch_bounds__(512, 2) void mega_kernel(
    const int* __restrict__ target, const int* __restrict__ tf,
    const float* __restrict__ dec_emb, const u16* __restrict__ x_emb,
    const u16* __restrict__ wp_e0, const u16* __restrict__ wp_e1, const u16* __restrict__ wp_e2,
    const u16* __restrict__ wp_d0f, const u16* __restrict__ wp_d1, const u16* __restrict__ wp_d2,
    const float* __restrict__ enc_b, const float* __restrict__ dec_b, const float* __restrict__ fb0,
    const float* __restrict__ lin_h_W1, const float* __restrict__ lin_c_W1, const float* __restrict__ lin_a_W1,
    const float* __restrict__ lin_h_W2, const float* __restrict__ lin_c_W2, const float* __restrict__ lin_a_W2,
    const float* __restrict__ bias2d,
    const float* __restrict__ fc_W, const float* __restrict__ fc_b,
    float* __restrict__ out,
    float* __restrict__ h_all, float* __restrict__ tmp6, float* __restrict__ tmp6c,
    float* __restrict__ dec_c, float* __restrict__ enc_c,
    u16* __restrict__ hseq, u16* __restrict__ dec_hA, u16* __restrict__ dec_hB,
    u16* __restrict__ bufA, u16* __restrict__ bufB, u16* __restrict__ cat,
    u16* __restrict__ eo_bf, u32* __restrict__ barblk)
{
  __shared__ SharedU sh;
  __shared__ u32 ord_sh;
  const int bid = blockIdx.x, tid = threadIdx.x;
  u32* ctr = barblk + 336;
  u32* badflag = barblk + 352;
  u32 gs = 0, gf = 0;

  // ---- mode detect ----
  u32 xcc;
  asm volatile("s_getreg_b32 %0, hwreg(HW_REG_XCC_ID)" : "=s"(xcc));
  xcc &= 7u;
  if (tid == 0){
    u32 o = __hip_atomic_fetch_add(&ctr[xcc], 1u, __ATOMIC_RELAXED, __HIP_MEMORY_SCOPE_AGENT);
    ord_sh = o;
    if (o >= 32u)
      __hip_atomic_store(badflag, 1u, __ATOMIC_RELAXED, __HIP_MEMORY_SCOPE_AGENT);
  }
  ++gs; bar_slow(barblk, gs, bid);
  bool fast = (__hip_atomic_load(badflag, __ATOMIC_RELAXED, __HIP_MEMORY_SCOPE_AGENT) == 0u);
  int mt, y;
  if (fast){ mt = (int)xcc; y = (int)ord_sh; }
  else     { mt = bid & 7;  y = bid >> 3;    }
  const int half = tid >> 8, htid = tid & 255;
  const int b = mt*32 + y;

  // worker role for encoder: 32 blocks = 16 batch-tiles x 2 dirs.
  // fast: 4 per XCD (ord<4), dir by XCD half -> 4 same-(l,d) blocks share one L2-resident W.
  bool worker; int wdir, wtile;
  if (fast){ worker = (y < 4); wdir = mt >> 2; wtile = (mt & 3)*4 + y; }
  else     { worker = (bid < 32); wdir = bid >> 4; wtile = bid & 15; }
  const int m0 = wtile*16;

  // -------- encoder: 3 layer passes, barrier-free recurrence, 3 slow barriers --------
  if (worker)
    enc_pass<256>(&sh, m0, wdir, x_emb, x_emb, (size_t)BH, wp_e0, enc_b + wdir*1024,
                  hseq + (size_t)(0+wdir)*BH, h_all + (size_t)(0+wdir)*BH, enc_c + (size_t)(0+wdir)*BH);
  ++gs; bar_slow(barblk, gs, bid);
  if (worker)
    enc_pass<512>(&sh, m0, wdir, hseq + 0*(size_t)BH, hseq + 1*(size_t)BH, (size_t)(DD*BH),
                  wp_e1, enc_b + 2048 + wdir*1024,
                  hseq + (size_t)(2+wdir)*BH, h_all + (size_t)(2+wdir)*BH, enc_c + (size_t)(2+wdir)*BH);
  ++gs; bar_slow(barblk, gs, bid);
  if (worker)
    enc_pass<512>(&sh, m0, wdir, hseq + 2*(size_t)BH, hseq + 3*(size_t)BH, (size_t)(DD*BH),
                  wp_e2, enc_b + 4096 + wdir*1024,
                  hseq + (size_t)(4+wdir)*BH, h_all + (size_t)(4+wdir)*BH, enc_c + (size_t)(4+wdir)*BH);
  ++gs; bar_slow(barblk, gs, bid);   // publishes hseq/h_all/enc_c to all XCDs

  // -------- bridges (round-6 proven; XCD-local tiles) --------
  {
    if (half == 0) mix_one(b, htid, h_all + (size_t)31*DD*BH, tmp6,  lin_h_W2, 0);
    else           mix_one(b, htid, enc_c,                    tmp6c, lin_c_W2, 0);
    __syncthreads();
    for (int t2 = half*16; t2 < half*16 + 16; t2++)
      mix_one(b, htid, h_all, h_all, lin_a_W2, t2);
  }
  if (fast){ ++gf; bar_fast(barblk, mt, gf); } else { ++gs; bar_slow(barblk, gs, bid); }
  if (y < 6){
    if (half == 0) gemm_tile(sh.gm2[0], htid, y*256 + mt*32, tmp6,  nullptr, lin_h_W1, bias2d + 1536, dec_hA);
    else           gemm_tile(sh.gm2[1], htid, y*256 + mt*32, tmp6c, dec_c,   lin_c_W1, bias2d + 3072, nullptr);
  }
  #pragma unroll
  for (int jj = 0; jj < 3; jj++){
    int k2 = y*6 + half*3 + jj;
    gemm_tile(sh.gm2[half], htid, k2*256 + mt*32, h_all, nullptr, lin_a_W1, bias2d, eo_bf);
  }
  if (fast){ ++gf; bar_fast(barblk, mt, gf); } else { ++gs; bar_slow(barblk, gs, bid); }

  // -------- decoder: 28 steps x (attn+fc | stage0 | stage1 | stage2) --------
  float* attn_out = out + (size_t)TOUT*BB*VDEC;
  for (int i = 0; i < TOUT-1; i++){
    const u16* hRb = (i & 1) ? dec_hB : dec_hA;
    u16*       hWb = (i & 1) ? dec_hA : dec_hB;
    attn_phase(&sh, b, i, hRb, eo_bf, cat, tf, attn_out, target, out, dec_emb, bufA, fc_W, fc_b);
    if (fast){ ++gf; bar_fast(barblk, mt, gf); } else { ++gs; bar_slow(barblk, gs, bid); }
    stage_dec<512>(&sh, mt, y, cat,  wp_d0f, fb0,          hRb, hWb, dec_c, bufA, 0);
    if (fast){ ++gf; bar_fast(barblk, mt, gf); } else { ++gs; bar_slow(barblk, gs, bid); }
    stage_dec<512>(&sh, mt, y, bufA, wp_d1,  dec_b + 2048, hRb, hWb, dec_c, bufB, 1);
    if (fast){ ++gf; bar_fast(barblk, mt, gf); } else { ++gs; bar_slow(barblk, gs, bid); }
    stage_dec<512>(&sh, mt, y, bufB, wp_d2,  dec_b + 4096, hRb, hWb, dec_c, bufA, 2);
    if (fast){ ++gf; bar_fast(barblk, mt, gf); } else { ++gs; bar_slow(barblk, gs, bid); }
  }
  fc_final_phase(&sh, b, bufA, fc_W, fc_b, out);
}

// =====================================================================

extern "C" void kernel_launch(void* const* d_in, const int* in_sizes, int n_in,
                              void* d_out, int out_size, void* d_ws, size_t ws_size,
                              hipStream_t stream){
  (void)in_sizes; (void)n_in; (void)out_size; (void)ws_size;
  const int*   input    = (const int*)d_in[0];
  const int*   target   = (const int*)d_in[1];
  const int*   tf       = (const int*)d_in[2];
  const float* enc_emb  = (const float*)d_in[3];
  const float* dec_emb  = (const float*)d_in[4];
  const float* enc_Wih0 = (const float*)d_in[5];
  const float* enc_Wih1 = (const float*)d_in[6];
  const float* enc_Whh  = (const float*)d_in[7];
  const float* enc_b    = (const float*)d_in[8];
  const float* dec_Wih0 = (const float*)d_in[9];
  const float* dec_Wih1 = (const float*)d_in[10];
  const float* dec_Whh  = (const float*)d_in[11];
  const float* dec_b    = (const float*)d_in[12];
  const float* lin_h_W1 = (const float*)d_in[13];
  const float* lin_h_b1 = (const float*)d_in[14];
  const float* lin_h_W2 = (const float*)d_in[15];
  const float* lin_h_b2 = (const float*)d_in[16];
  const float* lin_c_W1 = (const float*)d_in[17];
  const float* lin_c_b1 = (const float*)d_in[18];
  const float* lin_c_W2 = (const float*)d_in[19];
  const float* lin_c_b2 = (const float*)d_in[20];
  const float* lin_a_W1 = (const float*)d_in[21];
  const float* lin_a_b1 = (const float*)d_in[22];
  const float* lin_a_W2 = (const float*)d_in[23];
  const float* lin_a_b2 = (const float*)d_in[24];
  const float* attn_W   = (const float*)d_in[25];
  const float* attn_b   = (const float*)d_in[26];
  const float* fc_W     = (const float*)d_in[27];
  const float* fc_b     = (const float*)d_in[28];
  float* out = (float*)d_out;

  char* base = (char*)d_ws;
  size_t off = 0;
  auto alloc = [&](size_t bytes)->char*{
    char* p = base + off; off += (bytes + 255) & ~(size_t)255; return p;
  };
  float* h_all  = (float*)alloc(sizeof(float)*(size_t)TIN*DD*BH);
  float* tmp6   = (float*)alloc(sizeof(float)*(size_t)DD*BH);
  float* tmp6c  = (float*)alloc(sizeof(float)*(size_t)DD*BH);
  float* dec_c  = (float*)alloc(sizeof(float)*(size_t)DD*BH);
  float* bias2d = (float*)alloc(sizeof(float)*3*6*256);
  float* enc_c  = (float*)alloc(sizeof(float)*(size_t)DD*BH);
  u16* hseq   = (u16*)alloc(sizeof(u16)*(size_t)TIN*DD*BH);    // encoder h sequence (bf16)
  u16* dec_hA = (u16*)alloc(sizeof(u16)*(size_t)DD*BH);
  u16* dec_hB = (u16*)alloc(sizeof(u16)*(size_t)DD*BH);
  u16* x_emb  = (u16*)alloc(sizeof(u16)*(size_t)TIN*BB*EDIM);
  u16* bufA   = (u16*)alloc(sizeof(u16)*(size_t)BB*512);
  u16* bufB   = (u16*)alloc(sizeof(u16)*(size_t)BB*512);
  u16* cat    = (u16*)alloc(sizeof(u16)*(size_t)BB*512);
  u16* eo_bf  = (u16*)alloc(sizeof(u16)*(size_t)TIN*DD*BH);
  u16* wp_e0  = (u16*)alloc(sizeof(u16)*(size_t)2048*512);
  u16* wp_e1  = (u16*)alloc(sizeof(u16)*(size_t)2048*768);
  u16* wp_e2  = (u16*)alloc(sizeof(u16)*(size_t)2048*768);
  u16* wp_d0f = (u16*)alloc(sizeof(u16)*(size_t)2048*768);
  u16* wp_d1  = (u16*)alloc(sizeof(u16)*(size_t)2048*768);
  u16* wp_d2  = (u16*)alloc(sizeof(u16)*(size_t)2048*768);
  float* fb0  = (float*)alloc(sizeof(float)*2048);
  u32* barblk = (u32*)alloc(sizeof(u32)*1024);

  const int outn = TOUT*BB*VDEC + TOUT*TIN*DD*BB;
  init_out_kernel<<<(outn+255)/256, 256, 0, stream>>>(out, outn);
  fill_zero_u32<<<4, 256, 0, stream>>>(barblk, 1024);
  bias2d_kernel<<<1, 256, 0, stream>>>(lin_a_W2, lin_a_b1, lin_a_b2,
                                       lin_h_W2, lin_h_b1, lin_h_b2,
                                       lin_c_W2, lin_c_b1, lin_c_b2, bias2d);
  embed_enc_kernel<<<(TIN*BB*EDIM)/256, 256, 0, stream>>>(input, enc_emb, x_emb);
  pack_w_kernel<<<dim3(2,2048), 256, 0, stream>>>(enc_Wih0, enc_Whh,                       wp_e0, 256, 512);
  pack_w_kernel<<<dim3(3,2048), 256, 0, stream>>>(enc_Wih1, enc_Whh + 2*1024*256,          wp_e1, 512, 768);
  pack_w_kernel<<<dim3(3,2048), 256, 0, stream>>>(enc_Wih1 + (size_t)2*1024*512, enc_Whh + 4*1024*256, wp_e2, 512, 768);
  pack_wfused_kernel<<<dim3(3,2048), 256, 0, stream>>>(dec_Wih0, attn_W, dec_Whh,          wp_d0f);
  biasfold_kernel<<<8, 256, 0, stream>>>(dec_Wih0, attn_b, dec_b, fb0);
  pack_w_kernel<<<dim3(3,2048), 256, 0, stream>>>(dec_Wih1, dec_Whh + 2*1024*256,          wp_d1, 512, 768);
  pack_w_kernel<<<dim3(3,2048), 256, 0, stream>>>(dec_Wih1 + (size_t)2*1024*512, dec_Whh + 4*1024*256, wp_d2, 512, 768);

  mega_kernel<<<NBLK, 512, 0, stream>>>(
      target, tf, dec_emb, x_emb,
      wp_e0, wp_e1, wp_e2, wp_d0f, wp_d1, wp_d2,
      enc_b, dec_b, fb0,
      lin_h_W1, lin_c_W1, lin_a_W1, lin_h_W2, lin_c_W2, lin_a_W2,
      bias2d, fc_W, fc_b, out,
      h_all, tmp6, tmp6c, dec_c, enc_c, hseq, dec_hA, dec_hB,
      bufA, bufB, cat, eo_bf, barblk);
}